// Round 9
// baseline (464.621 us; speedup 1.0000x reference)
//
#include <hip/hip_runtime.h>
#include <math.h>

#define SEQ    2048
#define NBATCH 4
#define NTOK   8192
#define EMB    768
#define DFF    3072
#define NH     8
#define HD     96
#define QSEG   6291456   // 32 pairs * 2048 * 96

typedef float            f32x4  __attribute__((ext_vector_type(4)));
typedef float            f32x16 __attribute__((ext_vector_type(16)));
typedef __bf16           bf16x8 __attribute__((ext_vector_type(8)));
typedef unsigned short   u16;
typedef unsigned int     u32;
typedef int              i32x2  __attribute__((ext_vector_type(2)));
typedef u16              u16x8  __attribute__((ext_vector_type(8)));
typedef u16              u16x4  __attribute__((ext_vector_type(4)));

__device__ __forceinline__ u16 f2bf(float f) {
  union { float f; unsigned u; } v; v.f = f;
  unsigned r = v.u + 0x7FFFu + ((v.u >> 16) & 1u);
  return (u16)(r >> 16);
}
__device__ __forceinline__ bf16x8 asbf(u16x8 v) { return __builtin_bit_cast(bf16x8, v); }
__device__ __forceinline__ u32 pk2(float a, float b) {
  union { __bf16 h[2]; u32 w; } u; u.h[0] = (__bf16)a; u.h[1] = (__bf16)b; return u.w;
}

__device__ __forceinline__ void gload16(const void* g, void* l) {
  __builtin_amdgcn_global_load_lds((const __attribute__((address_space(1))) unsigned*)g,
                                   (__attribute__((address_space(3))) unsigned*)l, 16, 0, 0);
}

// ---------------------------------------------------------------------------
// fp32 [R][C] -> bf16 transposed [C][R]
// ---------------------------------------------------------------------------
__global__ __launch_bounds__(256)
void transpose_cvt(const float* __restrict__ in, u16* __restrict__ out, int R, int C) {
  __shared__ float tile[32][33];
  const int c0 = blockIdx.x * 32, r0 = blockIdx.y * 32;
  const int tr = threadIdx.x >> 5, tc = threadIdx.x & 31;
#pragma unroll
  for (int i = 0; i < 4; ++i)
    tile[tr + 8 * i][tc] = in[(size_t)(r0 + tr + 8 * i) * C + c0 + tc];
  __syncthreads();
#pragma unroll
  for (int i = 0; i < 4; ++i)
    out[(size_t)(c0 + tr + 8 * i) * R + r0 + tc] = f2bf(tile[tc][tr + 8 * i]);
}

__global__ __launch_bounds__(256)
void concat_bias(const float* __restrict__ bq, const float* __restrict__ bk,
                 const float* __restrict__ bv, float* __restrict__ out) {
  int i = blockIdx.x * 256 + threadIdx.x;
  if (i < 2304) {
    const float* s = (i < 768) ? bq : ((i < 1536) ? bk : bv);
    out[i] = s[i % 768];
  }
}

// ---------------------------------------------------------------------------
// LayerNorm: fp32 [rows][768] -> bf16 [rows][768]; one wave per row
// ---------------------------------------------------------------------------
__global__ __launch_bounds__(256)
void ln_k(const float* __restrict__ x, const float* __restrict__ g,
          const float* __restrict__ b, u16* __restrict__ y) {
  const int row = blockIdx.x * 4 + (threadIdx.x >> 6);
  const int l = threadIdx.x & 63;
  const float* xr = x + (size_t)row * EMB;
  f32x4 v[3];
#pragma unroll
  for (int i = 0; i < 3; ++i) v[i] = *(const f32x4*)(xr + (l + 64 * i) * 4);
  float s = 0.f;
#pragma unroll
  for (int i = 0; i < 3; ++i)
#pragma unroll
    for (int j = 0; j < 4; ++j) s += v[i][j];
#pragma unroll
  for (int m = 32; m; m >>= 1) s += __shfl_xor(s, m, 64);
  const float mu = s * (1.0f / EMB);
  float q = 0.f;
#pragma unroll
  for (int i = 0; i < 3; ++i)
#pragma unroll
    for (int j = 0; j < 4; ++j) { float d = v[i][j] - mu; q += d * d; }
#pragma unroll
  for (int m = 32; m; m >>= 1) q += __shfl_xor(q, m, 64);
  const float rstd = rsqrtf(q * (1.0f / EMB) + 1e-5f);
#pragma unroll
  for (int i = 0; i < 3; ++i) {
    const int c0 = (l + 64 * i) * 4;
    f32x4 gv = *(const f32x4*)(g + c0);
    f32x4 bv = *(const f32x4*)(b + c0);
    u16x4 o;
#pragma unroll
    for (int j = 0; j < 4; ++j) o[j] = f2bf((v[i][j] - mu) * rstd * gv[j] + bv[j]);
    *(u16x4*)(y + (size_t)row * EMB + c0) = o;
  }
}

// ---------------------------------------------------------------------------
// GEMM v8: 8-phase 256x256 template (m201 structure, plain HIP).
// BK=64, 512 thr / 8 waves (2Mx4N), wave output 128x64 (acc[8][4] f32x4).
// 2-slot LDS (A,B 32KB each per slot = 128KB). 4 phases per K-tile:
//   phase q reads A-half (q>>1) [row quarters {h,h+2}], B-half (q&1)
//   [row eighths], 12x ds_read_b128 -> 16 MFMA (4mf x 2nf x 2ks).
// Stage schedule (unit dead across all waves before issue; two barriers
// per phase make the ledger airtight):
//   ph0: A#1 of tile t+1 -> slot^1    ph1: B#1 of tile t+1 -> slot^1
//   ph2: A#0 of tile t+2 -> slot      ph3: B#0 of tile t+2 -> slot
// vmcnt(4) ONCE per tile at ph3 boundary (drains tile t+1, leaves t+2's
// 4 loads in flight); chunk-XOR swizzle on global src + ds_read (G21);
// setprio around MFMA cluster (T5).
// EPI 0: QKV scatter (Q,K [p][tok][d]; V via LDS transpose -> [p][d][tok]).
// EPI 2: +bias exact GELU -> bf16 row-major.
// ---------------------------------------------------------------------------
template <int EPI>
__global__ __launch_bounds__(512, 2)
void gemm8_k(const u16* __restrict__ A, const u16* __restrict__ BT,
             const float* __restrict__ bias, void* __restrict__ outp,
             int M, int N, int K, int nbn) {
  __shared__ __align__(16) u16 smem[67584];   // 132KB (staging 128KB; V-epi 135KB pad reuse)
  u16* sA = smem;                              // [2][16384]
  u16* sB = smem + 32768;                      // [2][16384]
  const int t = threadIdx.x;
  const int w = t >> 6, l = t & 63;
  const int wr = w >> 2, wc = w & 3;
  const int lr = l & 15, lg = l >> 4;
  const int cpx = gridDim.x >> 3;
  const int bid = (blockIdx.x & 7) * cpx + (blockIdx.x >> 3);
  const int bm = bid / nbn, bn = bid - bm * nbn;
  const int m0 = bm << 8, n0 = bn << 8;

  // staging maps: unit = 128 rows x 64 cols = 16KB; 2 loads/thread.
  // A#0 rows {0-63,128-191}, A#1 +64; B#0 rows {0-31,64-95,128-159,192-223}, B#1 +32.
  int ldA0[2], ldA1[2], ldB0[2], ldB1[2];
  size_t gaA0[2], gaA1[2], gaB0[2], gaB1[2];
#pragma unroll
  for (int j = 0; j < 2; ++j) {
    const int u = t + j * 512, i = u >> 3, c = u & 7;
    const int r0 = ((i >> 6) << 7) | (i & 63);
    const int r1 = r0 + 64;
    const int s0 = ((i >> 5) << 6) | (i & 31);
    const int s1 = s0 + 32;
    ldA0[j] = r0 * 64 + c * 8;  gaA0[j] = (size_t)(m0 + r0) * K + ((c ^ (r0 & 7)) * 8);
    ldA1[j] = r1 * 64 + c * 8;  gaA1[j] = (size_t)(m0 + r1) * K + ((c ^ (r1 & 7)) * 8);
    ldB0[j] = s0 * 64 + c * 8;  gaB0[j] = (size_t)(n0 + s0) * K + ((c ^ (s0 & 7)) * 8);
    ldB1[j] = s1 * 64 + c * 8;  gaB1[j] = (size_t)(n0 + s1) * K + ((c ^ (s1 & 7)) * 8);
  }

#define STG_A0(sl, tt_) { _Pragma("unroll") for (int j = 0; j < 2; ++j) \
    gload16(A + gaA0[j] + (tt_) * 64, sA + (sl) * 16384 + ldA0[j]); }
#define STG_A1(sl, tt_) { _Pragma("unroll") for (int j = 0; j < 2; ++j) \
    gload16(A + gaA1[j] + (tt_) * 64, sA + (sl) * 16384 + ldA1[j]); }
#define STG_B0(sl, tt_) { _Pragma("unroll") for (int j = 0; j < 2; ++j) \
    gload16(BT + gaB0[j] + (tt_) * 64, sB + (sl) * 16384 + ldB0[j]); }
#define STG_B1(sl, tt_) { _Pragma("unroll") for (int j = 0; j < 2; ++j) \
    gload16(BT + gaB1[j] + (tt_) * 64, sB + (sl) * 16384 + ldB1[j]); }

  f32x4 acc[8][4] = {};
  const int NT = K >> 6;

  // prologue: tile0 full (8) + tile1 first halves (4); vmcnt(4) = tile0 ready
  STG_A0(0, 0); STG_B0(0, 0); STG_A1(0, 0); STG_B1(0, 0);
  STG_A0(1, 1); STG_B0(1, 1);
  asm volatile("s_waitcnt vmcnt(4)" ::: "memory");
  __builtin_amdgcn_s_barrier();

  for (int tt = 0; tt < NT; ++tt) {
    const int slot = tt & 1;
#pragma unroll
    for (int q = 0; q < 4; ++q) {
      // ds_read quadrant frags
      bf16x8 af[4][2], bfv[2][2];
#pragma unroll
      for (int m = 0; m < 4; ++m) {
        const int row = wr * 128 + (q >> 1) * 64 + m * 16 + lr;
#pragma unroll
        for (int ks = 0; ks < 2; ++ks) {
          const int ch = (ks * 4 + lg) ^ (row & 7);
          af[m][ks] = asbf(*(const u16x8*)(sA + slot * 16384 + row * 64 + ch * 8));
        }
      }
#pragma unroll
      for (int n = 0; n < 2; ++n) {
        const int row = wc * 64 + (q & 1) * 32 + n * 16 + lr;
#pragma unroll
        for (int ks = 0; ks < 2; ++ks) {
          const int ch = (ks * 4 + lg) ^ (row & 7);
          bfv[n][ks] = asbf(*(const u16x8*)(sB + slot * 16384 + row * 64 + ch * 8));
        }
      }
      // stage per dead-set schedule
      if (q == 0) { if (tt + 1 < NT) STG_A1(slot ^ 1, tt + 1); }
      if (q == 1) { if (tt + 1 < NT) STG_B1(slot ^ 1, tt + 1); }
      if (q == 2) { if (tt + 2 < NT) STG_A0(slot, tt + 2); }
      if (q == 3) { if (tt + 2 < NT) STG_B0(slot, tt + 2); }
      __builtin_amdgcn_s_barrier();
      __builtin_amdgcn_s_setprio(1);
#pragma unroll
      for (int ks = 0; ks < 2; ++ks)
#pragma unroll
        for (int m = 0; m < 4; ++m)
#pragma unroll
          for (int n = 0; n < 2; ++n)
            acc[(q >> 1) * 4 + m][(q & 1) * 2 + n] =
                __builtin_amdgcn_mfma_f32_16x16x32_bf16(af[m][ks], bfv[n][ks],
                    acc[(q >> 1) * 4 + m][(q & 1) * 2 + n], 0, 0, 0);
      __builtin_amdgcn_s_setprio(0);
      if (q == 3) {   // tile boundary: tile t+1 must be complete
        if (tt + 2 < NT) asm volatile("s_waitcnt vmcnt(4)" ::: "memory");
        else if (tt + 1 < NT) asm volatile("s_waitcnt vmcnt(0)" ::: "memory");
      }
      __builtin_amdgcn_s_barrier();
    }
  }
#undef STG_A0
#undef STG_A1
#undef STG_B0
#undef STG_B1

  // epilogue: C/D frag layout col=lane&15, row=(lane>>4)*4+j
  if (EPI == 0) {
    const int whichB = n0 / 768;            // 256-tiles lie wholly in Q/K/V
    if (whichB < 2) {
      u16* qb = (u16*)outp + (size_t)whichB * QSEG;
#pragma unroll
      for (int nf = 0; nf < 4; ++nf) {
        const int col = n0 + wc * 64 + nf * 16 + lr;
        const int cm = col - whichB * 768;
        const int h = cm / 96, d = cm - h * 96;
        const float bcol = bias[col];
#pragma unroll
        for (int mf = 0; mf < 8; ++mf)
#pragma unroll
          for (int j = 0; j < 4; ++j) {
            const int row = m0 + wr * 128 + mf * 16 + lg * 4 + j;
            const int b = row >> 11, tok = row & 2047;
            qb[((size_t)((b * NH + h) * SEQ + tok)) * HD + d] = f2bf(acc[mf][nf][j] + bcol);
          }
      }
    } else {
      // V: LDS transpose -> V^T [p][d][tok], 16B full-line stores
      __syncthreads();
      u16* tp = smem;                       // [256 cols][264 rows pad]
      const int colb = wc * 64 + lr;
#pragma unroll
      for (int nf = 0; nf < 4; ++nf) {
        const float bcol = bias[n0 + colb + nf * 16];
#pragma unroll
        for (int mf = 0; mf < 8; ++mf) {
          u16x4 o4;
#pragma unroll
          for (int j = 0; j < 4; ++j) o4[j] = f2bf(acc[mf][nf][j] + bcol);
          *(u16x4*)(tp + (colb + nf * 16) * 264 + wr * 128 + mf * 16 + lg * 4) = o4;
        }
      }
      __syncthreads();
      const int c = t >> 1, half = t & 1;
      const int cm = n0 + c - 1536;
      const int h = cm / 96, d = cm - h * 96;
      const int b = m0 >> 11;
      const int tok0 = (m0 & 2047) + half * 128;
      u16* vb = (u16*)outp + 2 * (size_t)QSEG +
                ((size_t)((b * NH + h) * HD + d)) * SEQ + tok0;
      const u16* src = tp + c * 264 + half * 128;
#pragma unroll
      for (int i = 0; i < 16; ++i)
        *(u16x8*)(vb + i * 8) = *(const u16x8*)(src + i * 8);
    }
  } else {  // EPI 2: GELU -> bf16 row-major
#pragma unroll
    for (int nf = 0; nf < 4; ++nf) {
      const int col = n0 + wc * 64 + nf * 16 + lr;
      const float bcol = bias[col];
#pragma unroll
      for (int mf = 0; mf < 8; ++mf)
#pragma unroll
        for (int j = 0; j < 4; ++j) {
          const int row = m0 + wr * 128 + mf * 16 + lg * 4 + j;
          const float v = acc[mf][nf][j] + bcol;
          ((u16*)outp)[(size_t)row * N + col] =
              f2bf(0.5f * v * (1.0f + erff(v * 0.70710678f)));
        }
    }
  }
}

// ---------------------------------------------------------------------------
// GEMM v3: 128x128, 4 waves, triple-slot depth-2 (unchanged, proven).
// O-proj (EPI 1) and FFN2 (EPI 3): +bias +resid -> fp32. Grid 384.
// ---------------------------------------------------------------------------
template <int EPI>
__global__ __launch_bounds__(256, 3)
void gemm3_k(const u16* __restrict__ A, const u16* __restrict__ BT,
             const float* __restrict__ bias, const float* __restrict__ resid,
             float* __restrict__ outp, int M, int N, int K, int nbn) {
  __shared__ __align__(16) u16 sA[3][4096];
  __shared__ __align__(16) u16 sB[3][4096];
  const int t = threadIdx.x;
  const int w = t >> 6, l = t & 63;
  const int wr = w >> 1, wc = w & 1;
  const int lr = l & 15, lg = l >> 4;
  const int cpx = gridDim.x >> 3;
  const int bid = (blockIdx.x & 7) * cpx + (blockIdx.x >> 3);
  const int bm = bid / nbn, bn = bid - bm * nbn;
  const int m0 = bm << 7, n0 = bn << 7;

  const int rS = t >> 2, cS = t & 3;
  const int cG0 = cS ^ ((rS >> 1) & 3);
  const int cG1 = cS ^ (((rS + 64) >> 1) & 3);
  const u16* gA0 = A + (size_t)(m0 + rS) * K + cG0 * 8;
  const u16* gA1 = A + (size_t)(m0 + rS + 64) * K + cG1 * 8;
  const u16* gB0 = BT + (size_t)(n0 + rS) * K + cG0 * 8;
  const u16* gB1 = BT + (size_t)(n0 + rS + 64) * K + cG1 * 8;

#define G3STAGE(slot, kel) {                          \
    gload16(gA0 + (kel), &sA[slot][t * 8]);           \
    gload16(gA1 + (kel), &sA[slot][2048 + t * 8]);    \
    gload16(gB0 + (kel), &sB[slot][t * 8]);           \
    gload16(gB1 + (kel), &sB[slot][2048 + t * 8]); }

  const int swz = (lr >> 1) & 3;
  const int offA = (wr * 64 + lr) * 32 + ((lg ^ swz) * 8);
  const int offB = (wc * 64 + lr) * 32 + ((lg ^ swz) * 8);

  f32x4 acc[4][4] = {};
  G3STAGE(0, 0);
  G3STAGE(1, 32);
  G3STAGE(2, 64);
  asm volatile("s_waitcnt vmcnt(8)" ::: "memory");
  __builtin_amdgcn_s_barrier();

  const int NT = K >> 5;
  int slot = 0;
  for (int ti = 0; ti < NT; ++ti) {
    bf16x8 af[4], bf[4];
#pragma unroll
    for (int mf = 0; mf < 4; ++mf)
      af[mf] = asbf(*(const u16x8*)(&sA[slot][offA + mf * 512]));
#pragma unroll
    for (int nf = 0; nf < 4; ++nf)
      bf[nf] = asbf(*(const u16x8*)(&sB[slot][offB + nf * 512]));
    __builtin_amdgcn_s_setprio(1);
#pragma unroll
    for (int mf = 0; mf < 4; ++mf)
#pragma unroll
      for (int nf = 0; nf < 4; ++nf)
        acc[mf][nf] = __builtin_amdgcn_mfma_f32_16x16x32_bf16(af[mf], bf[nf], acc[mf][nf], 0, 0, 0);
    __builtin_amdgcn_s_setprio(0);
    __builtin_amdgcn_s_barrier();
    if (ti + 3 < NT) {
      G3STAGE(slot, (ti + 3) * 32);
      asm volatile("s_waitcnt vmcnt(4)" ::: "memory");
    } else if (ti + 2 == NT) {
      asm volatile("s_waitcnt vmcnt(0)" ::: "memory");
    }
    __builtin_amdgcn_s_barrier();
    ++slot; if (slot == 3) slot = 0;
  }
#undef G3STAGE

#pragma unroll
  for (int nf = 0; nf < 4; ++nf) {
    const int col = n0 + wc * 64 + nf * 16 + lr;
    const float bcol = bias[col];
#pragma unroll
    for (int mf = 0; mf < 4; ++mf)
#pragma unroll
      for (int j = 0; j < 4; ++j) {
        const int row = m0 + wr * 64 + mf * 16 + lg * 4 + j;
        const size_t off = (size_t)row * N + col;
        outp[off] = acc[mf][nf][j] + bcol + resid[off];
      }
  }
}

// ---------------------------------------------------------------------------
// Flash attention, swapped 32x32 structure, 4 waves/block (unchanged).
// ---------------------------------------------------------------------------
__global__ __launch_bounds__(256, 2)
void attn_k(const u16* __restrict__ qkv, u16* __restrict__ obuf) {
  __shared__ __align__(16) u16 sK[2][64 * 128];
  __shared__ __align__(16) u16 sV[2][96 * 64];
  const int bid = blockIdx.x;
  const int x = bid & 7, i = bid >> 3;
  const int p = x * 4 + (i & 3), qt = i >> 2;
  const int t = threadIdx.x;
  const int w = t >> 6, l = t & 63;
  const int hl = l >> 5, lm = l & 31;
  const u16* qb  = qkv + (size_t)p * SEQ * HD;
  const u16* kb  = qb + QSEG;
  const u16* vtb = qkv + 2 * (size_t)QSEG + (size_t)p * SEQ * HD;
  const int q0w = qt * 128 + w * 32;

  bf16x8 qf[6];
#pragma unroll
  for (int ds = 0; ds < 6; ++ds)
    qf[ds] = asbf(*(const u16x8*)(qb + (size_t)(q0w + lm) * HD + ds * 16 + hl * 8));

  const int ccK = (t & 15) ^ ((t >> 4) & 7);
  const int koff = (t >> 4) * HD + ccK * 8;
  const int kld  = (t >> 4) * 128 + (t & 15) * 8;
  const int ccV = (t & 7) ^ ((t >> 3) & 7);
  const int voff = (t >> 3) * SEQ + ccV * 8;
  const int vld  = (t >> 3) * 64 + (t & 7) * 8;

#define ASTAGE(bi, kt_) {                                        \
    const u16* kbase = kb + (size_t)(kt_) * 64 * HD + koff;      \
    gload16(kbase,        &sK[bi][kld]);                         \
    gload16(kbase + 1536, &sK[bi][kld + 2048]);                  \
    gload16(kbase + 3072, &sK[bi][kld + 4096]);                  \
    gload16(kbase + 4608, &sK[bi][kld + 6144]);                  \
    const u16* vbase = vtb + (kt_) * 64 + voff;                  \
    gload16(vbase,            &sV[bi][vld]);                     \
    gload16(vbase + 32 * SEQ, &sV[bi][vld + 2048]);              \
    gload16(vbase + 64 * SEQ, &sV[bi][vld + 4096]); }

  f32x16 oacc[3] = {};
  float mreg = -1e30f, lsum = 0.f;
  int cur = 0;

  ASTAGE(0, 0);
  for (int kt = 0; kt < 32; ++kt) {
    asm volatile("s_waitcnt vmcnt(0)" ::: "memory");
    __syncthreads();
    if (kt < 31) ASTAGE(cur ^ 1, kt + 1);

    f32x16 st[2] = {};
#pragma unroll
    for (int tile = 0; tile < 2; ++tile)
#pragma unroll
      for (int ds = 0; ds < 6; ++ds) {
        const int row = tile * 32 + lm;
        const int cs = (2 * ds + hl) ^ (l & 7);
        bf16x8 kf = asbf(*(const u16x8*)(&sK[cur][row * 128 + cs * 8]));
        st[tile] = __builtin_amdgcn_mfma_f32_32x32x16_bf16(kf, qf[ds], st[tile], 0, 0, 0);
      }

    float mx[8];
#pragma unroll
    for (int r = 0; r < 8; ++r)
      mx[r] = fmaxf(fmaxf(st[0][r], st[0][r + 8]), fmaxf(st[1][r], st[1][r + 8]));
#pragma unroll
    for (int s = 4; s; s >>= 1)
#pragma unroll
      for (int r = 0; r < s; ++r) mx[r] = fmaxf(mx[r], mx[r + s]);
    float pmax = fmaxf(mx[0], __shfl_xor(mx[0], 32, 64));
    if (__any(pmax > mreg + 8.f)) {   // defer-max (T13)
      const float mn = fmaxf(mreg, pmax);
      const float al = __expf(mreg - mn);
      mreg = mn; lsum *= al;
#pragma unroll
      for (int d3 = 0; d3 < 3; ++d3)
#pragma unroll
        for (int r = 0; r < 16; ++r) oacc[d3][r] *= al;
    }
    float ts = 0.f;
    u32 wds[16];
#pragma unroll
    for (int g = 0; g < 8; ++g) {
      const float e0 = __expf(st[(4 * g) >> 4][(4 * g) & 15] - mreg);
      const float e1 = __expf(st[(4 * g + 1) >> 4][(4 * g + 1) & 15] - mreg);
      const float e2 = __expf(st[(4 * g + 2) >> 4][(4 * g + 2) & 15] - mreg);
      const float e3 = __expf(st[(4 * g + 3) >> 4][(4 * g + 3) & 15] - mreg);
      ts += (e0 + e1) + (e2 + e3);
      wds[2 * g]     = pk2(e0, e1);
      wds[2 * g + 1] = pk2(e2, e3);
    }
    ts += __shfl_xor(ts, 32, 64);
    lsum += ts;

#pragma unroll
    for (int s = 0; s < 4; ++s) {
      i32x2 r02 = __builtin_amdgcn_permlane32_swap((int)wds[4 * s], (int)wds[4 * s + 2], false, false);
      i32x2 r13 = __builtin_amdgcn_permlane32_swap((int)wds[4 * s + 1], (int)wds[4 * s + 3], false, false);
      union { u32 wu[4]; bf16x8 v; } pu;
      pu.wu[0] = (u32)r02[0]; pu.wu[1] = (u32)r13[0];
      pu.wu[2] = (u32)r02[1]; pu.wu[3] = (u32)r13[1];
      const bf16x8 pf = pu.v;
#pragma unroll
      for (int d3 = 0; d3 < 3; ++d3) {
        const int row = d3 * 32 + lm;
        const int cs = (2 * s + hl) ^ (l & 7);
        bf16x8 vf = asbf(*(const u16x8*)(&sV[cur][row * 64 + cs * 8]));
        oacc[d3] = __builtin_amdgcn_mfma_f32_32x32x16_bf16(vf, pf, oacc[d3], 0, 0, 0);
      }
    }
    cur ^= 1;
  }

  const int b = p >> 3, h = p & 7;
  const float sc = 0.03608439182435161f / lsum;
  u16* ob = obuf + (size_t)(b * SEQ + q0w + lm) * EMB + h * HD;
#pragma unroll
  for (int d3 = 0; d3 < 3; ++d3)
#pragma unroll
    for (int g = 0; g < 4; ++g) {
      u16x4 o4;
#pragma unroll
      for (int j = 0; j < 4; ++j) o4[j] = f2bf(oacc[d3][4 * g + j] * sc);
      *(u16x4*)(ob + d3 * 32 + 8 * g + 4 * hl) = o4;
    }
#undef ASTAGE
}

// ---------------------------------------------------------------------------
extern "C" void kernel_launch(void* const* d_in, const int* in_sizes, int n_in,
                              void* d_out, int out_size, void* d_ws, size_t ws_size,
                              hipStream_t stream) {
  const float* x    = (const float*)d_in[0];
  const float* ln1g = (const float*)d_in[1];
  const float* ln1b = (const float*)d_in[2];
  const float* wq   = (const float*)d_in[3];
  const float* bq   = (const float*)d_in[4];
  const float* wk   = (const float*)d_in[5];
  const float* bk   = (const float*)d_in[6];
  const float* wv   = (const float*)d_in[7];
  const float* bv   = (const float*)d_in[8];
  const float* wo   = (const float*)d_in[9];
  const float* bo   = (const float*)d_in[10];
  const float* ln2g = (const float*)d_in[11];
  const float* ln2b = (const float*)d_in[12];
  const float* w1   = (const float*)d_in[13];
  const float* b1   = (const float*)d_in[14];
  const float* w2   = (const float*)d_in[15];
  const float* b2   = (const float*)d_in[16];
  float* out = (float*)d_out;

  char* ws = (char*)d_ws;
  u16* wqkvT  = (u16*)ws;   ws += (size_t)2304 * 768 * 2;
  u16* woT    = (u16*)ws;   ws += (size_t)768 * 768 * 2;
  u16* w1T    = (u16*)ws;   ws += (size_t)3072 * 768 * 2;
  u16* w2T    = (u16*)ws;   ws += (size_t)768 * 3072 * 2;
  float* bqkv = (float*)ws; ws += (size_t)2304 * 4;
  u16* bufA   = (u16*)ws;   ws += (size_t)NTOK * EMB * 2;   // y -> o -> z
  u16* bigbuf = (u16*)ws;   ws += (size_t)NTOK * DFF * 2;   // qkv -> ffn hidden
  float* x1   = (float*)ws; ws += (size_t)NTOK * EMB * 4;

  transpose_cvt<<<dim3(24, 24), 256, 0, stream>>>(wq, wqkvT, 768, 768);
  transpose_cvt<<<dim3(24, 24), 256, 0, stream>>>(wk, wqkvT + 768 * 768, 768, 768);
  transpose_cvt<<<dim3(24, 24), 256, 0, stream>>>(wv, wqkvT + 2 * 768 * 768, 768, 768);
  transpose_cvt<<<dim3(24, 24), 256, 0, stream>>>(wo, woT, 768, 768);
  transpose_cvt<<<dim3(96, 24), 256, 0, stream>>>(w1, w1T, 768, 3072);
  transpose_cvt<<<dim3(24, 96), 256, 0, stream>>>(w2, w2T, 3072, 768);
  concat_bias<<<9, 256, 0, stream>>>(bq, bk, bv, bqkv);

  ln_k<<<NTOK / 4, 256, 0, stream>>>(x, ln1g, ln1b, bufA);
  // QKV projection: 8-phase 256x256 (32 x 9 = 288 blocks)
  gemm8_k<0><<<288, 512, 0, stream>>>(bufA, wqkvT, bqkv, bigbuf, NTOK, 2304, 768, 9);
  attn_k<<<512, 256, 0, stream>>>(bigbuf, bufA);
  gemm3_k<1><<<384, 256, 0, stream>>>(bufA, woT, bo, x, x1, NTOK, 768, 768, 6);
  ln_k<<<NTOK / 4, 256, 0, stream>>>(x1, ln2g, ln2b, bufA);
  // FFN1 + GELU: 8-phase 256x256 (32 x 12 = 384 blocks)
  gemm8_k<2><<<384, 512, 0, stream>>>(bufA, w1T, b1, bigbuf, NTOK, 3072, 768, 12);
  gemm3_k<3><<<384, 256, 0, stream>>>(bigbuf, w2T, b2, x1, out, NTOK, 768, 3072, 6);
}